// Round 17
// baseline (324.545 us; speedup 1.0000x reference)
//
#include <hip/hip_runtime.h>
#include <hip/hip_bf16.h>

typedef unsigned short u16;
typedef unsigned int u32;
typedef unsigned char u8;
typedef long long ll8;                                   // 8 x fp8 operand
typedef __attribute__((ext_vector_type(4))) float f4v;   // mfma acc

__device__ __forceinline__ float rcpf(float x) { return __builtin_amdgcn_rcpf(x); }
__device__ __forceinline__ float ex2(float x) {
#if __has_builtin(__builtin_amdgcn_exp2f)
  return __builtin_amdgcn_exp2f(x);
#else
  return exp2f(x);
#endif
}
__device__ __forceinline__ float sigf(float x) { return rcpf(1.0f + __expf(-x)); }
// pack 2 floats -> 2 fp8 e4m3 bytes into low/high 16b word of old (HI immediate)
template<bool HI>
__device__ __forceinline__ u32 pkfp8(float a, float b, u32 old) {
  return (u32)__builtin_amdgcn_cvt_pk_fp8_f32(a, b, (int)old, HI);
}
__device__ __forceinline__ u8 f2f8(float x) { return (u8)(pkfp8<false>(x, x, 0) & 0xffu); }
// fp8 e4m3 byte (selected from u32) -> f32
template<int S>
__device__ __forceinline__ float f8tof(u32 v) {
#if __has_builtin(__builtin_amdgcn_cvt_f32_fp8)
  return __builtin_amdgcn_cvt_f32_fp8((int)v, S);
#else
  u8 b = (u8)(v >> (8 * S));
  u32 s = (b >> 7) & 1u, e = (b >> 3) & 15u, m = b & 7u;
  union { u32 i; float f; } r;
  if (e) r.i = (s << 31) | ((e + 120u) << 23) | (m << 20);
  else { r.f = (float)m * 0.001953125f; r.i |= s << 31; }
  return r.f;
#endif
}

#define GS_IFO 1.4426950408889634f
#define GS_G   2.8853900817779268f

__device__ __forceinline__ void gl_lds16(const void* g, void* l) {
  __builtin_amdgcn_global_load_lds(
      (const __attribute__((address_space(1))) u32*)g,
      (__attribute__((address_space(3))) u32*)l, 16, 0, 0);
}

// ---------------- weight conversion fp32 -> fp8 (all weights) ----------------
struct CvtArgs {
  const float* src[9];
  u8* dst[9];
  int n4[9];
  int scl[9];
  int sh[9];
};
__global__ __launch_bounds__(256) void k_cvt(CvtArgs a) {
  int seg = blockIdx.y;
  int i = blockIdx.x * 256 + threadIdx.x;
  if (i >= a.n4[seg]) return;
  float4 v = ((const float4*)a.src[seg])[i];
  float s;
  if (a.scl[seg] == 2) {
    s = GS_IFO;
  } else {
    int r = i >> a.sh[seg];
    s = (((r >> 7) & 3) == 2) ? GS_G : GS_IFO;
  }
  v.x *= s; v.y *= s; v.z *= s; v.w *= s;
  u32 p = pkfp8<false>(v.x, v.y, 0);
  p = pkfp8<true>(v.z, v.w, p);
  ((u32*)a.dst[seg])[i] = p;
}

// ------- transpose input [B,C,H,W] -> fp8 x [(b,w,h)][c] (full 256-c rows per block);
//         also channel sums. grid (64 h, 16 b). 256 B u32 writes. -------
__global__ __launch_bounds__(256) void k_tin(const float* __restrict__ in,
                                             u8* __restrict__ A8,
                                             float* __restrict__ meansum) {
  int h = blockIdx.x, b = blockIdx.y;
  int t = threadIdx.x, lane = t & 63, q = t >> 6;
  __shared__ u8 lT[64][260];                 // [w][c], pad 260 (65 words) -> 2-way max
  const float* src = in + (b * 256 * 64 + h) * 64;
#pragma unroll 4
  for (int i = 0; i < 64; ++i) {
    int c = q * 64 + i;                      // each q-group covers 64 channels
    float v = src[c * 4096 + lane];
    lT[lane][c] = f2f8(v);
    float s = v;
#pragma unroll
    for (int off = 32; off; off >>= 1) s += __shfl_xor(s, off);
    if (lane == 0) atomicAdd(&meansum[b * 256 + c], s);
  }
  __syncthreads();
  // write: 64 w-rows x 64 u32-chunks; wave covers one w-row's 256 B contiguously
  u8* dst = A8 + (b * 4096 + h) * 256;
  int cu = lane;                             // u32 chunk 0..63
#pragma unroll 4
  for (int i = 0; i < 16; ++i) {
    int w = q * 16 + i;
    const u8* lp = &lT[w][cu << 2];
    u32 v = (u32)lp[0] | ((u32)lp[1] << 8) | ((u32)lp[2] << 16) | ((u32)lp[3] << 24);
    *(u32*)(dst + w * 16384 + (cu << 2)) = v;
  }
}

// ------- q_avg[b][o] = softmax_o( Wl[o,:] . mean_c ) -------
__global__ __launch_bounds__(256) void k_qavg(const float* __restrict__ meansum,
                                              const float* __restrict__ Wl,
                                              float* __restrict__ qavg) {
  int b = blockIdx.x, t = threadIdx.x;
  __shared__ float mean[256];
  __shared__ float red[256];
  mean[t] = meansum[b * 256 + t] * (1.0f / 4096.0f);
  __syncthreads();
  const float* wr = Wl + t * 256;
  float acc = 0.0f;
  for (int c = 0; c < 256; ++c) acc = fmaf(wr[c], mean[c], acc);
  red[t] = acc; __syncthreads();
  for (int s = 128; s; s >>= 1) { if (t < s) red[t] = fmaxf(red[t], red[t + s]); __syncthreads(); }
  float mx = red[0]; __syncthreads();
  float e = __expf(acc - mx);
  red[t] = e; __syncthreads();
  for (int s = 128; s; s >>= 1) { if (t < s) red[t] += red[t + s]; __syncthreads(); }
  qavg[b * 256 + t] = e / red[0];
}

// ------- 128x128 fp8 GEMM, full-K resident (Wr path): VF=fp8(exp2(A.W)), Zsum atomics ----
__global__ __launch_bounds__(256, 2) void k_gemm8(const u8* __restrict__ A,
                                                  const u8* __restrict__ W,
                                                  u8* __restrict__ out,
                                                  float* __restrict__ Zsum) {
  int nwg = gridDim.x;
  int q = nwg >> 3;
  int bid = blockIdx.x;
  int swz = (bid & 7) * q + (bid >> 3);
  int mt = swz >> 1, nt = swz & 1;          // NT = 2
  int mb = mt << 7, nb = nt << 7;
  int t = threadIdx.x, lane = t & 63, wid = t >> 6;
  int laneg = lane & 15, lk = lane >> 4;
  __shared__ __align__(16) u8 lA[128][256];
  __shared__ __align__(16) u8 lW[128][256];
  {
    int rl = lane >> 4;                     // 0..3 row within 4-row round
    int unit = lane & 15;
#pragma unroll
    for (int i = 0; i < 8; ++i) {
      int rb4 = ((wid << 3) + i) << 2;      // 4-row block base
      int r = rb4 + rl;
      int usA = unit ^ (r & 7);
      gl_lds16(A + (mb + r) * 256 + (usA << 4), &lA[rb4][0]);
      gl_lds16(W + (nb + r) * 256 + (usA << 4), &lW[rb4][0]);
    }
  }
  __syncthreads();
  f4v acc[4][4] = {};
  int wm = wid >> 1, wn = wid & 1;
#pragma unroll
  for (int kk = 0; kk < 8; ++kk) {
    ll8 af[4], bf[4];
#pragma unroll
    for (int m = 0; m < 4; ++m) {
      int r = (wm << 6) + (m << 4) + laneg;
      int us = ((kk << 1) + (lk >> 1)) ^ (r & 7);
      af[m] = *(const ll8*)&lA[r][(us << 4) + ((lk & 1) << 3)];
    }
#pragma unroll
    for (int n = 0; n < 4; ++n) {
      int r = (wn << 6) + (n << 4) + laneg;
      int us = ((kk << 1) + (lk >> 1)) ^ (r & 7);
      bf[n] = *(const ll8*)&lW[r][(us << 4) + ((lk & 1) << 3)];
    }
#pragma unroll
    for (int m = 0; m < 4; ++m)
#pragma unroll
      for (int n = 0; n < 4; ++n)
        acc[m][n] = __builtin_amdgcn_mfma_f32_16x16x32_fp8_fp8(af[m], bf[n], acc[m][n], 0, 0, 0);
  }
#pragma unroll
  for (int n = 0; n < 4; ++n) {
    int col = nb + (wn << 6) + (n << 4) + laneg;
    float csum = 0.f;
#pragma unroll
    for (int m = 0; m < 4; ++m) {
      int row0 = mb + (wm << 6) + (m << 4) + (lk << 2);
#pragma unroll
      for (int j = 0; j < 4; ++j) {
        float e = ex2(acc[m][n][j]);
        csum += e;
        out[(row0 + j) * 256 + col] = f2f8(e);
      }
    }
    csum += __shfl_xor(csum, 16);
    csum += __shfl_xor(csum, 32);
    if (lk == 0) atomicAdd(&Zsum[((mb >> 12) << 8) + col], csum);
  }
}

// ------- FUSED biLSTM v8: fp8 datapath, 2-step-unrolled nacc ping-pong (no acc copies),
//         setprio around h-MFMA, vmcnt(2) guard, lgkm-only barrier. (unchanged R16) -------
__global__ __launch_bounds__(512, 1) void k_recur_f(const u8* __restrict__ X8,
                                                    const u8* __restrict__ Wi8,
                                                    const u8* __restrict__ Wh8d,
                                                    const float* __restrict__ bias_f,
                                                    const float* __restrict__ bias_b,
                                                    u8* __restrict__ outb) {
  int dir = blockIdx.y;
  int s0 = blockIdx.x << 4;                 // 16 sequences per block
  int t = threadIdx.x, lane = t & 63, w = t >> 6;  // 8 waves
  int laneg = lane & 15, lk = lane >> 4;
  const u8* Wd = Wh8d + dir * 65536;
  const u8* Wi = Wi8 + dir * 131072;
  const float* bia = dir ? bias_b : bias_f;
  int hc = w << 4;
  ll8 bfr[4][4];
#pragma unroll
  for (int g = 0; g < 4; ++g)
#pragma unroll
    for (int kk = 0; kk < 4; ++kk)
      bfr[g][kk] = *(const ll8*)(Wd + (g * 128 + hc + laneg) * 128 + kk * 32 + lk * 8);
  ll8 ifr[4][8];
#pragma unroll
  for (int g = 0; g < 4; ++g)
#pragma unroll
    for (int kk = 0; kk < 8; ++kk)
      ifr[g][kk] = *(const ll8*)(Wi + (g * 128 + hc + laneg) * 256 + kk * 32 + lk * 8);
  float bval[4];
#pragma unroll
  for (int g = 0; g < 4; ++g)
    bval[g] = bia[g * 128 + hc + laneg] * ((g == 2) ? GS_G : GS_IFO);

  __shared__ __align__(16) u8 hb[2][16][144];   // fp8 h double-buffer
  __shared__ __align__(16) u8 xb[4][16][256];   // fp8 x tiles (dist-3 prefetch)
  for (int i = t; i < 2 * 16 * 144; i += 512) ((u8*)hb)[i] = 0;

  float cs[4] = {0.f, 0.f, 0.f, 0.f};
  int tc0 = dir ? 63 : 0;
  int dstep = dir ? -1 : 1;
  int srw = (w << 2) + (lane >> 4);         // 0..15 for w<4
  int c16 = lane & 15;
  const u8* xsrc = X8 + (s0 + srw) * 16384 + ((c16 ^ (srw & 7)) << 4);
  int srow = t >> 5;                        // 0..15
  int schunk = t & 31;                      // 0..31
  int rowb = ((s0 >> 6) << 12) + (s0 & 63);

  auto wihx = [&](f4v (&a)[4], const u8* xrow) {
    ll8 xf[8];
#pragma unroll
    for (int kk = 0; kk < 8; ++kk)
      xf[kk] = *(const ll8*)&xrow[((((kk << 1) + (lk >> 1)) ^ (laneg & 7)) << 4) + ((lk & 1) << 3)];
#pragma unroll
    for (int g = 0; g < 4; ++g)
#pragma unroll
      for (int kk = 0; kk < 8; ++kk)
        a[g] = __builtin_amdgcn_mfma_f32_16x16x32_fp8_fp8(xf[kk], ifr[g][kk], a[g], 0, 0, 0);
  };

  if (w < 4) {
    gl_lds16(xsrc + tc0 * 256, &xb[0][w << 2][0]);
    gl_lds16(xsrc + (tc0 + dstep) * 256, &xb[1][w << 2][0]);
    gl_lds16(xsrc + (tc0 + 2 * dstep) * 256, &xb[2][w << 2][0]);
  }
  __syncthreads();
  f4v naccP[4], naccQ[4];
#pragma unroll
  for (int g = 0; g < 4; ++g) {
    naccP[g] = (f4v){bval[g], bval[g], bval[g], bval[g]};
    naccQ[g] = naccP[g];
  }
  wihx(naccP, &xb[0][laneg][0]);
  wihx(naccQ, &xb[1][laneg][0]);

  int cur = 0;
  for (int st = 0; st < 64; st += 2) {
    {
      int tc = tc0 + st * dstep;
      if (st) {
        int pr = tc - dstep;
        u32 hv = *(const u32*)&hb[cur][srow][schunk << 2];
        *(u32*)(outb + (rowb + pr * 64 + srow) * 256 + (dir << 7) + (schunk << 2)) = hv;
      }
      if (w < 4 && st < 61)
        gl_lds16(xsrc + (tc0 + (st + 3) * dstep) * 256, &xb[(st + 3) & 3][w << 2][0]);
      __builtin_amdgcn_s_setprio(1);
      {
        ll8 afr[4];
#pragma unroll
        for (int kk = 0; kk < 4; ++kk)
          afr[kk] = *(const ll8*)&hb[cur][laneg][kk * 32 + lk * 8];
#pragma unroll
        for (int g = 0; g < 4; ++g)
#pragma unroll
          for (int kk = 0; kk < 4; ++kk)
            naccP[g] = __builtin_amdgcn_mfma_f32_16x16x32_fp8_fp8(afr[kk], bfr[g][kk], naccP[g], 0, 0, 0);
      }
      __builtin_amdgcn_s_setprio(0);
      int nxt = cur ^ 1;
#pragma unroll
      for (int j = 0; j < 4; ++j) {
        float Y = ex2(-naccP[0][j]);
        float V = ex2(-naccP[1][j]);
        float X = ex2(naccP[2][j]);
        float Wo = ex2(-naccP[3][j]);
        float ig = (X - 1.0f) * rcpf((1.0f + Y) * (X + 1.0f));
        float c = cs[j] * rcpf(1.0f + V) + ig;
        cs[j] = c;
        float Z = ex2(c * GS_G);
        float h = (Z - 1.0f) * rcpf((1.0f + Wo) * (Z + 1.0f));
        hb[nxt][(lk << 2) + j][hc + laneg] = f2f8(h);
      }
      if (st < 62) {
        if (st == 0) { asm volatile("s_waitcnt vmcnt(1)" ::: "memory"); }
        else         { asm volatile("s_waitcnt vmcnt(2)" ::: "memory"); }
#pragma unroll
        for (int g = 0; g < 4; ++g)
          naccP[g] = (f4v){bval[g], bval[g], bval[g], bval[g]};
        wihx(naccP, &xb[(st + 2) & 3][laneg][0]);
      }
      asm volatile("s_waitcnt lgkmcnt(0)" ::: "memory");
      __builtin_amdgcn_s_barrier();
      cur = nxt;
    }
    {
      int so = st + 1;
      int tc = tc0 + so * dstep;
      {
        int pr = tc - dstep;
        u32 hv = *(const u32*)&hb[cur][srow][schunk << 2];
        *(u32*)(outb + (rowb + pr * 64 + srow) * 256 + (dir << 7) + (schunk << 2)) = hv;
      }
      if (w < 4 && so < 61)
        gl_lds16(xsrc + (tc0 + (so + 3) * dstep) * 256, &xb[(so + 3) & 3][w << 2][0]);
      __builtin_amdgcn_s_setprio(1);
      {
        ll8 afr[4];
#pragma unroll
        for (int kk = 0; kk < 4; ++kk)
          afr[kk] = *(const ll8*)&hb[cur][laneg][kk * 32 + lk * 8];
#pragma unroll
        for (int g = 0; g < 4; ++g)
#pragma unroll
          for (int kk = 0; kk < 4; ++kk)
            naccQ[g] = __builtin_amdgcn_mfma_f32_16x16x32_fp8_fp8(afr[kk], bfr[g][kk], naccQ[g], 0, 0, 0);
      }
      __builtin_amdgcn_s_setprio(0);
      int nxt = cur ^ 1;
#pragma unroll
      for (int j = 0; j < 4; ++j) {
        float Y = ex2(-naccQ[0][j]);
        float V = ex2(-naccQ[1][j]);
        float X = ex2(naccQ[2][j]);
        float Wo = ex2(-naccQ[3][j]);
        float ig = (X - 1.0f) * rcpf((1.0f + Y) * (X + 1.0f));
        float c = cs[j] * rcpf(1.0f + V) + ig;
        cs[j] = c;
        float Z = ex2(c * GS_G);
        float h = (Z - 1.0f) * rcpf((1.0f + Wo) * (Z + 1.0f));
        hb[nxt][(lk << 2) + j][hc + laneg] = f2f8(h);
      }
      if (so < 62) {
        asm volatile("s_waitcnt vmcnt(2)" ::: "memory");
#pragma unroll
        for (int g = 0; g < 4; ++g)
          naccQ[g] = (f4v){bval[g], bval[g], bval[g], bval[g]};
        wihx(naccQ, &xb[(so + 2) & 3][laneg][0]);
      }
      asm volatile("s_waitcnt lgkmcnt(0)" ::: "memory");
      __builtin_amdgcn_s_barrier();
      cur = nxt;
    }
  }
  {
    int pr = tc0 + 63 * dstep;
    u32 hv = *(const u32*)&hb[cur][srow][schunk << 2];
    *(u32*)(outb + (rowb + pr * 64 + srow) * 256 + (dir << 7) + (schunk << 2)) = hv;
  }
}

// ------- fused attention + final, 256-sp blocks: 1 KB float4 reads/writes.
//         grid (16 spg, 16 b), 256 threads. -------
__global__ __launch_bounds__(256) void k_attfin(const u8* __restrict__ VF8,
                                                const float* __restrict__ qavg,
                                                const float* __restrict__ Z,
                                                const float* __restrict__ in,
                                                const float* __restrict__ alpha,
                                                float* __restrict__ out) {
  int spg = blockIdx.x;                      // 256-spatial group
  int b = blockIdx.y;
  int sp0 = spg << 8;
  int t = threadIdx.x, lane = t & 63, wid = t >> 6;
  __shared__ __align__(16) float lwo[256];
  __shared__ __align__(16) float fac[256];
  lwo[t] = qavg[b * 256 + t] / Z[b * 256 + t];
  __syncthreads();
  float4 wo = *(const float4*)&lwo[lane * 4];
  int rowbase = b * 4096 + sp0;
  // phase 1: att for 256 rows; each wave handles 64 rows
#pragma unroll 4
  for (int i = 0; i < 64; ++i) {
    int r = wid * 64 + i;
    u32 v = *(const u32*)&VF8[(rowbase + r) * 256 + lane * 4];
    float p = wo.x * f8tof<0>(v) + wo.y * f8tof<1>(v) +
              wo.z * f8tof<2>(v) + wo.w * f8tof<3>(v);
#pragma unroll
    for (int off = 32; off; off >>= 1) p += __shfl_xor(p, off);
    if (lane == 0) fac[r] = p;
  }
  __syncthreads();
  float al = alpha[0];
  fac[t] = 1.0f + al * sigf(fac[t]);
  __syncthreads();
  // phase 2: scale 256 c x 256 sp; wave covers one c-row's 1 KB contiguously
  float4 f4 = *(const float4*)&fac[lane << 2];
  const float4* ip = (const float4*)(in + (long)b * 1048576 + sp0) ;
  float4* op = (float4*)(out + (long)b * 1048576 + sp0);
#pragma unroll 4
  for (int c = wid; c < 256; c += 4) {
    float4 v = ip[c * 1024 + lane];
    float4 r;
    r.x = v.x * f4.x; r.y = v.y * f4.y; r.z = v.z * f4.z; r.w = v.w * f4.w;
    op[c * 1024 + lane] = r;
  }
}

extern "C" void kernel_launch(void* const* d_in, const int* in_sizes, int n_in,
                              void* d_out, int out_size, void* d_ws, size_t ws_size,
                              hipStream_t stream) {
  const float* input   = (const float*)d_in[0];
  const float* h_Wih_f = (const float*)d_in[1];
  const float* h_Whh_f = (const float*)d_in[2];
  const float* h_b_f   = (const float*)d_in[3];
  const float* h_Wih_b = (const float*)d_in[4];
  const float* h_Whh_b = (const float*)d_in[5];
  const float* h_b_b   = (const float*)d_in[6];
  const float* v_Wih_f = (const float*)d_in[7];
  const float* v_Whh_f = (const float*)d_in[8];
  const float* v_b_f   = (const float*)d_in[9];
  const float* v_Wih_b = (const float*)d_in[10];
  const float* v_Whh_b = (const float*)d_in[11];
  const float* v_b_b   = (const float*)d_in[12];
  const float* Wr      = (const float*)d_in[13];
  const float* Wl      = (const float*)d_in[14];
  const float* alphap  = (const float*)d_in[15];

  char* ws = (char*)d_ws;
  u8*  Ah8   = (u8*)(ws + 0);              // 16,777,216 B fp8 x (stage1); later Ar8
  u8*  VF8   = (u8*)(ws + 33554432);       // 16,777,216 B fp8 evf
  u8*  Wh8   = (u8*)(ws + 67108864);       // 262,144 fp8 [2][512][256]
  u8*  Wv8   = (u8*)(ws + 67371008);       // 262,144
  u8*  WhhH8 = (u8*)(ws + 67633152);       // 131,072 fp8 [2][512][128]
  u8*  WhhV8 = (u8*)(ws + 67764224);       // 131,072
  u8*  Wrb8  = (u8*)(ws + 67895296);       // 65,536 fp8 [256][256]
  float* meansum = (float*)(ws + 67960832);  // 16 KB
  float* qavg    = (float*)(ws + 67977216);  // 16 KB
  float* pZ      = (float*)(ws + 67993600);  // 16 KB
  u8*  Av8 = (u8*)d_out;                   // stage1 fp8 output (16.7MB, dead before attfin)
  u8*  Ar8 = Ah8;                          // stage2 fp8 output over dead Ah8

  (void)hipMemsetAsync(meansum, 0, 3 * 16384, stream);  // meansum + qavg + pZ

  CvtArgs ca;
  ca.src[0] = h_Wih_f; ca.dst[0] = Wh8;           ca.n4[0] = 32768; ca.scl[0] = 1; ca.sh[0] = 6;
  ca.src[1] = h_Wih_b; ca.dst[1] = Wh8 + 131072;  ca.n4[1] = 32768; ca.scl[1] = 1; ca.sh[1] = 6;
  ca.src[2] = v_Wih_f; ca.dst[2] = Wv8;           ca.n4[2] = 32768; ca.scl[2] = 1; ca.sh[2] = 6;
  ca.src[3] = v_Wih_b; ca.dst[3] = Wv8 + 131072;  ca.n4[3] = 32768; ca.scl[3] = 1; ca.sh[3] = 6;
  ca.src[4] = h_Whh_f; ca.dst[4] = WhhH8;         ca.n4[4] = 16384; ca.scl[4] = 1; ca.sh[4] = 5;
  ca.src[5] = h_Whh_b; ca.dst[5] = WhhH8 + 65536; ca.n4[5] = 16384; ca.scl[5] = 1; ca.sh[5] = 5;
  ca.src[6] = v_Whh_f; ca.dst[6] = WhhV8;         ca.n4[6] = 16384; ca.scl[6] = 1; ca.sh[6] = 5;
  ca.src[7] = v_Whh_b; ca.dst[7] = WhhV8 + 65536; ca.n4[7] = 16384; ca.scl[7] = 1; ca.sh[7] = 5;
  ca.src[8] = Wr;      ca.dst[8] = Wrb8;          ca.n4[8] = 16384; ca.scl[8] = 2; ca.sh[8] = 6;
  k_cvt<<<dim3(128, 9), 256, 0, stream>>>(ca);

  k_tin<<<dim3(64, 16), 256, 0, stream>>>(input, Ah8, meansum);
  k_qavg<<<16, 256, 0, stream>>>(meansum, Wl, qavg);

  k_recur_f<<<dim3(64, 2), 512, 0, stream>>>(Ah8, Wh8, WhhH8, h_b_f, h_b_b, Av8);
  k_recur_f<<<dim3(64, 2), 512, 0, stream>>>(Av8, Wv8, WhhV8, v_b_f, v_b_b, Ar8);
  k_gemm8<<<1024, 256, 0, stream>>>(Ar8, Wrb8, VF8, pZ);

  k_attfin<<<dim3(16, 16), 256, 0, stream>>>(VF8, qavg, pZ, input, alphap, (float*)d_out);
}

// Round 18
// 299.786 us; speedup vs baseline: 1.0826x; 1.0826x over previous
//
#include <hip/hip_runtime.h>
#include <hip/hip_bf16.h>

typedef unsigned short u16;
typedef unsigned int u32;
typedef unsigned char u8;
typedef long long ll8;                                   // 8 x fp8 operand
typedef __attribute__((ext_vector_type(4))) float f4v;   // mfma acc

__device__ __forceinline__ float rcpf(float x) { return __builtin_amdgcn_rcpf(x); }
__device__ __forceinline__ float ex2(float x) {
#if __has_builtin(__builtin_amdgcn_exp2f)
  return __builtin_amdgcn_exp2f(x);
#else
  return exp2f(x);
#endif
}
__device__ __forceinline__ float sigf(float x) { return rcpf(1.0f + __expf(-x)); }
// pack 2 floats -> 2 fp8 e4m3 bytes into low/high 16b word of old (HI immediate)
template<bool HI>
__device__ __forceinline__ u32 pkfp8(float a, float b, u32 old) {
  return (u32)__builtin_amdgcn_cvt_pk_fp8_f32(a, b, (int)old, HI);
}
__device__ __forceinline__ u8 f2f8(float x) { return (u8)(pkfp8<false>(x, x, 0) & 0xffu); }
// fp8 e4m3 byte (selected from u32) -> f32
template<int S>
__device__ __forceinline__ float f8tof(u32 v) {
#if __has_builtin(__builtin_amdgcn_cvt_f32_fp8)
  return __builtin_amdgcn_cvt_f32_fp8((int)v, S);
#else
  u8 b = (u8)(v >> (8 * S));
  u32 s = (b >> 7) & 1u, e = (b >> 3) & 15u, m = b & 7u;
  union { u32 i; float f; } r;
  if (e) r.i = (s << 31) | ((e + 120u) << 23) | (m << 20);
  else { r.f = (float)m * 0.001953125f; r.i |= s << 31; }
  return r.f;
#endif
}

#define GS_IFO 1.4426950408889634f
#define GS_G   2.8853900817779268f

__device__ __forceinline__ void gl_lds16(const void* g, void* l) {
  __builtin_amdgcn_global_load_lds(
      (const __attribute__((address_space(1))) u32*)g,
      (__attribute__((address_space(3))) u32*)l, 16, 0, 0);
}

// ---------------- weight conversion fp32 -> fp8 (all weights) ----------------
struct CvtArgs {
  const float* src[9];
  u8* dst[9];
  int n4[9];
  int scl[9];
  int sh[9];
};
__global__ __launch_bounds__(256) void k_cvt(CvtArgs a) {
  int seg = blockIdx.y;
  int i = blockIdx.x * 256 + threadIdx.x;
  if (i >= a.n4[seg]) return;
  float4 v = ((const float4*)a.src[seg])[i];
  float s;
  if (a.scl[seg] == 2) {
    s = GS_IFO;
  } else {
    int r = i >> a.sh[seg];
    s = (((r >> 7) & 3) == 2) ? GS_G : GS_IFO;
  }
  v.x *= s; v.y *= s; v.z *= s; v.w *= s;
  u32 p = pkfp8<false>(v.x, v.y, 0);
  p = pkfp8<true>(v.z, v.w, p);
  ((u32*)a.dst[seg])[i] = p;
}

// ------- transpose input [B,C,H,W] -> fp8 x [(b,w,h)][c] (full 256-c rows per block);
//         also channel sums. grid (64 h, 16 b). 256 B u32 writes. -------
__global__ __launch_bounds__(256) void k_tin(const float* __restrict__ in,
                                             u8* __restrict__ A8,
                                             float* __restrict__ meansum) {
  int h = blockIdx.x, b = blockIdx.y;
  int t = threadIdx.x, lane = t & 63, q = t >> 6;
  __shared__ u8 lT[64][260];                 // [w][c], pad 260 -> conflict-light
  const float* src = in + (b * 256 * 64 + h) * 64;
#pragma unroll 4
  for (int i = 0; i < 64; ++i) {
    int c = q * 64 + i;                      // each q-group covers 64 channels
    float v = src[c * 4096 + lane];
    lT[lane][c] = f2f8(v);
    float s = v;
#pragma unroll
    for (int off = 32; off; off >>= 1) s += __shfl_xor(s, off);
    if (lane == 0) atomicAdd(&meansum[b * 256 + c], s);
  }
  __syncthreads();
  // write: 64 w-rows x 64 u32-chunks; wave covers one w-row's 256 B contiguously
  u8* dst = A8 + (b * 4096 + h) * 256;
  int cu = lane;                             // u32 chunk 0..63
#pragma unroll 4
  for (int i = 0; i < 16; ++i) {
    int w = q * 16 + i;
    const u8* lp = &lT[w][cu << 2];
    u32 v = (u32)lp[0] | ((u32)lp[1] << 8) | ((u32)lp[2] << 16) | ((u32)lp[3] << 24);
    *(u32*)(dst + w * 16384 + (cu << 2)) = v;
  }
}

// ------- q_avg[b][o] = softmax_o( Wl[o,:] . mean_c ) -------
__global__ __launch_bounds__(256) void k_qavg(const float* __restrict__ meansum,
                                              const float* __restrict__ Wl,
                                              float* __restrict__ qavg) {
  int b = blockIdx.x, t = threadIdx.x;
  __shared__ float mean[256];
  __shared__ float red[256];
  mean[t] = meansum[b * 256 + t] * (1.0f / 4096.0f);
  __syncthreads();
  const float* wr = Wl + t * 256;
  float acc = 0.0f;
  for (int c = 0; c < 256; ++c) acc = fmaf(wr[c], mean[c], acc);
  red[t] = acc; __syncthreads();
  for (int s = 128; s; s >>= 1) { if (t < s) red[t] = fmaxf(red[t], red[t + s]); __syncthreads(); }
  float mx = red[0]; __syncthreads();
  float e = __expf(acc - mx);
  red[t] = e; __syncthreads();
  for (int s = 128; s; s >>= 1) { if (t < s) red[t] += red[t + s]; __syncthreads(); }
  qavg[b * 256 + t] = e / red[0];
}

// ------- 128x128 fp8 GEMM, full-K resident (Wr path): VF=fp8(exp2(A.W)), Zsum atomics ----
__global__ __launch_bounds__(256, 2) void k_gemm8(const u8* __restrict__ A,
                                                  const u8* __restrict__ W,
                                                  u8* __restrict__ out,
                                                  float* __restrict__ Zsum) {
  int nwg = gridDim.x;
  int q = nwg >> 3;
  int bid = blockIdx.x;
  int swz = (bid & 7) * q + (bid >> 3);
  int mt = swz >> 1, nt = swz & 1;          // NT = 2
  int mb = mt << 7, nb = nt << 7;
  int t = threadIdx.x, lane = t & 63, wid = t >> 6;
  int laneg = lane & 15, lk = lane >> 4;
  __shared__ __align__(16) u8 lA[128][256];
  __shared__ __align__(16) u8 lW[128][256];
  {
    int rl = lane >> 4;                     // 0..3 row within 4-row round
    int unit = lane & 15;
#pragma unroll
    for (int i = 0; i < 8; ++i) {
      int rb4 = ((wid << 3) + i) << 2;      // 4-row block base
      int r = rb4 + rl;
      int usA = unit ^ (r & 7);
      gl_lds16(A + (mb + r) * 256 + (usA << 4), &lA[rb4][0]);
      gl_lds16(W + (nb + r) * 256 + (usA << 4), &lW[rb4][0]);
    }
  }
  __syncthreads();
  f4v acc[4][4] = {};
  int wm = wid >> 1, wn = wid & 1;
#pragma unroll
  for (int kk = 0; kk < 8; ++kk) {
    ll8 af[4], bf[4];
#pragma unroll
    for (int m = 0; m < 4; ++m) {
      int r = (wm << 6) + (m << 4) + laneg;
      int us = ((kk << 1) + (lk >> 1)) ^ (r & 7);
      af[m] = *(const ll8*)&lA[r][(us << 4) + ((lk & 1) << 3)];
    }
#pragma unroll
    for (int n = 0; n < 4; ++n) {
      int r = (wn << 6) + (n << 4) + laneg;
      int us = ((kk << 1) + (lk >> 1)) ^ (r & 7);
      bf[n] = *(const ll8*)&lW[r][(us << 4) + ((lk & 1) << 3)];
    }
#pragma unroll
    for (int m = 0; m < 4; ++m)
#pragma unroll
      for (int n = 0; n < 4; ++n)
        acc[m][n] = __builtin_amdgcn_mfma_f32_16x16x32_fp8_fp8(af[m], bf[n], acc[m][n], 0, 0, 0);
  }
#pragma unroll
  for (int n = 0; n < 4; ++n) {
    int col = nb + (wn << 6) + (n << 4) + laneg;
    float csum = 0.f;
#pragma unroll
    for (int m = 0; m < 4; ++m) {
      int row0 = mb + (wm << 6) + (m << 4) + (lk << 2);
#pragma unroll
      for (int j = 0; j < 4; ++j) {
        float e = ex2(acc[m][n][j]);
        csum += e;
        out[(row0 + j) * 256 + col] = f2f8(e);
      }
    }
    csum += __shfl_xor(csum, 16);
    csum += __shfl_xor(csum, 32);
    if (lk == 0) atomicAdd(&Zsum[((mb >> 12) << 8) + col], csum);
  }
}

// ------- FUSED biLSTM v8: fp8 datapath, 2-step-unrolled nacc ping-pong,
//         setprio around h-MFMA, vmcnt(2) guard, lgkm-only barrier. (unchanged) -------
__global__ __launch_bounds__(512, 1) void k_recur_f(const u8* __restrict__ X8,
                                                    const u8* __restrict__ Wi8,
                                                    const u8* __restrict__ Wh8d,
                                                    const float* __restrict__ bias_f,
                                                    const float* __restrict__ bias_b,
                                                    u8* __restrict__ outb) {
  int dir = blockIdx.y;
  int s0 = blockIdx.x << 4;                 // 16 sequences per block
  int t = threadIdx.x, lane = t & 63, w = t >> 6;  // 8 waves
  int laneg = lane & 15, lk = lane >> 4;
  const u8* Wd = Wh8d + dir * 65536;
  const u8* Wi = Wi8 + dir * 131072;
  const float* bia = dir ? bias_b : bias_f;
  int hc = w << 4;
  ll8 bfr[4][4];
#pragma unroll
  for (int g = 0; g < 4; ++g)
#pragma unroll
    for (int kk = 0; kk < 4; ++kk)
      bfr[g][kk] = *(const ll8*)(Wd + (g * 128 + hc + laneg) * 128 + kk * 32 + lk * 8);
  ll8 ifr[4][8];
#pragma unroll
  for (int g = 0; g < 4; ++g)
#pragma unroll
    for (int kk = 0; kk < 8; ++kk)
      ifr[g][kk] = *(const ll8*)(Wi + (g * 128 + hc + laneg) * 256 + kk * 32 + lk * 8);
  float bval[4];
#pragma unroll
  for (int g = 0; g < 4; ++g)
    bval[g] = bia[g * 128 + hc + laneg] * ((g == 2) ? GS_G : GS_IFO);

  __shared__ __align__(16) u8 hb[2][16][144];   // fp8 h double-buffer
  __shared__ __align__(16) u8 xb[4][16][256];   // fp8 x tiles (dist-3 prefetch)
  for (int i = t; i < 2 * 16 * 144; i += 512) ((u8*)hb)[i] = 0;

  float cs[4] = {0.f, 0.f, 0.f, 0.f};
  int tc0 = dir ? 63 : 0;
  int dstep = dir ? -1 : 1;
  int srw = (w << 2) + (lane >> 4);         // 0..15 for w<4
  int c16 = lane & 15;
  const u8* xsrc = X8 + (s0 + srw) * 16384 + ((c16 ^ (srw & 7)) << 4);
  int srow = t >> 5;                        // 0..15
  int schunk = t & 31;                      // 0..31
  int rowb = ((s0 >> 6) << 12) + (s0 & 63);

  auto wihx = [&](f4v (&a)[4], const u8* xrow) {
    ll8 xf[8];
#pragma unroll
    for (int kk = 0; kk < 8; ++kk)
      xf[kk] = *(const ll8*)&xrow[((((kk << 1) + (lk >> 1)) ^ (laneg & 7)) << 4) + ((lk & 1) << 3)];
#pragma unroll
    for (int g = 0; g < 4; ++g)
#pragma unroll
      for (int kk = 0; kk < 8; ++kk)
        a[g] = __builtin_amdgcn_mfma_f32_16x16x32_fp8_fp8(xf[kk], ifr[g][kk], a[g], 0, 0, 0);
  };

  if (w < 4) {
    gl_lds16(xsrc + tc0 * 256, &xb[0][w << 2][0]);
    gl_lds16(xsrc + (tc0 + dstep) * 256, &xb[1][w << 2][0]);
    gl_lds16(xsrc + (tc0 + 2 * dstep) * 256, &xb[2][w << 2][0]);
  }
  __syncthreads();
  f4v naccP[4], naccQ[4];
#pragma unroll
  for (int g = 0; g < 4; ++g) {
    naccP[g] = (f4v){bval[g], bval[g], bval[g], bval[g]};
    naccQ[g] = naccP[g];
  }
  wihx(naccP, &xb[0][laneg][0]);
  wihx(naccQ, &xb[1][laneg][0]);

  int cur = 0;
  for (int st = 0; st < 64; st += 2) {
    {
      int tc = tc0 + st * dstep;
      if (st) {
        int pr = tc - dstep;
        u32 hv = *(const u32*)&hb[cur][srow][schunk << 2];
        *(u32*)(outb + (rowb + pr * 64 + srow) * 256 + (dir << 7) + (schunk << 2)) = hv;
      }
      if (w < 4 && st < 61)
        gl_lds16(xsrc + (tc0 + (st + 3) * dstep) * 256, &xb[(st + 3) & 3][w << 2][0]);
      __builtin_amdgcn_s_setprio(1);
      {
        ll8 afr[4];
#pragma unroll
        for (int kk = 0; kk < 4; ++kk)
          afr[kk] = *(const ll8*)&hb[cur][laneg][kk * 32 + lk * 8];
#pragma unroll
        for (int g = 0; g < 4; ++g)
#pragma unroll
          for (int kk = 0; kk < 4; ++kk)
            naccP[g] = __builtin_amdgcn_mfma_f32_16x16x32_fp8_fp8(afr[kk], bfr[g][kk], naccP[g], 0, 0, 0);
      }
      __builtin_amdgcn_s_setprio(0);
      int nxt = cur ^ 1;
#pragma unroll
      for (int j = 0; j < 4; ++j) {
        float Y = ex2(-naccP[0][j]);
        float V = ex2(-naccP[1][j]);
        float X = ex2(naccP[2][j]);
        float Wo = ex2(-naccP[3][j]);
        float ig = (X - 1.0f) * rcpf((1.0f + Y) * (X + 1.0f));
        float c = cs[j] * rcpf(1.0f + V) + ig;
        cs[j] = c;
        float Z = ex2(c * GS_G);
        float h = (Z - 1.0f) * rcpf((1.0f + Wo) * (Z + 1.0f));
        hb[nxt][(lk << 2) + j][hc + laneg] = f2f8(h);
      }
      if (st < 62) {
        if (st == 0) { asm volatile("s_waitcnt vmcnt(1)" ::: "memory"); }
        else         { asm volatile("s_waitcnt vmcnt(2)" ::: "memory"); }
#pragma unroll
        for (int g = 0; g < 4; ++g)
          naccP[g] = (f4v){bval[g], bval[g], bval[g], bval[g]};
        wihx(naccP, &xb[(st + 2) & 3][laneg][0]);
      }
      asm volatile("s_waitcnt lgkmcnt(0)" ::: "memory");
      __builtin_amdgcn_s_barrier();
      cur = nxt;
    }
    {
      int so = st + 1;
      int tc = tc0 + so * dstep;
      {
        int pr = tc - dstep;
        u32 hv = *(const u32*)&hb[cur][srow][schunk << 2];
        *(u32*)(outb + (rowb + pr * 64 + srow) * 256 + (dir << 7) + (schunk << 2)) = hv;
      }
      if (w < 4 && so < 61)
        gl_lds16(xsrc + (tc0 + (so + 3) * dstep) * 256, &xb[(so + 3) & 3][w << 2][0]);
      __builtin_amdgcn_s_setprio(1);
      {
        ll8 afr[4];
#pragma unroll
        for (int kk = 0; kk < 4; ++kk)
          afr[kk] = *(const ll8*)&hb[cur][laneg][kk * 32 + lk * 8];
#pragma unroll
        for (int g = 0; g < 4; ++g)
#pragma unroll
          for (int kk = 0; kk < 4; ++kk)
            naccQ[g] = __builtin_amdgcn_mfma_f32_16x16x32_fp8_fp8(afr[kk], bfr[g][kk], naccQ[g], 0, 0, 0);
      }
      __builtin_amdgcn_s_setprio(0);
      int nxt = cur ^ 1;
#pragma unroll
      for (int j = 0; j < 4; ++j) {
        float Y = ex2(-naccQ[0][j]);
        float V = ex2(-naccQ[1][j]);
        float X = ex2(naccQ[2][j]);
        float Wo = ex2(-naccQ[3][j]);
        float ig = (X - 1.0f) * rcpf((1.0f + Y) * (X + 1.0f));
        float c = cs[j] * rcpf(1.0f + V) + ig;
        cs[j] = c;
        float Z = ex2(c * GS_G);
        float h = (Z - 1.0f) * rcpf((1.0f + Wo) * (Z + 1.0f));
        hb[nxt][(lk << 2) + j][hc + laneg] = f2f8(h);
      }
      if (so < 62) {
        asm volatile("s_waitcnt vmcnt(2)" ::: "memory");
#pragma unroll
        for (int g = 0; g < 4; ++g)
          naccQ[g] = (f4v){bval[g], bval[g], bval[g], bval[g]};
        wihx(naccQ, &xb[(so + 2) & 3][laneg][0]);
      }
      asm volatile("s_waitcnt lgkmcnt(0)" ::: "memory");
      __builtin_amdgcn_s_barrier();
      cur = nxt;
    }
  }
  {
    int pr = tc0 + 63 * dstep;
    u32 hv = *(const u32*)&hb[cur][srow][schunk << 2];
    *(u32*)(outb + (rowb + pr * 64 + srow) * 256 + (dir << 7) + (schunk << 2)) = hv;
  }
}

// ------- fused attention + final (R16 shape: 1024 blocks, 64-sp each) -------
__global__ __launch_bounds__(256) void k_attfin(const u8* __restrict__ VF8,
                                                const float* __restrict__ qavg,
                                                const float* __restrict__ Z,
                                                const float* __restrict__ in,
                                                const float* __restrict__ alpha,
                                                float* __restrict__ out) {
  int bx = blockIdx.x;
  int b = bx >> 6;
  int sp0 = (bx & 63) << 6;
  int t = threadIdx.x, lane = t & 63, wid = t >> 6;
  __shared__ __align__(16) float lwo[256];
  __shared__ float fac[64];
  lwo[t] = qavg[b * 256 + t] / Z[b * 256 + t];
  __syncthreads();
  float4 wo = *(const float4*)&lwo[lane * 4];
  int rowbase = b * 4096 + sp0;
#pragma unroll 4
  for (int i = 0; i < 16; ++i) {
    int r = wid * 16 + i;
    u32 v = *(const u32*)&VF8[(rowbase + r) * 256 + lane * 4];
    float p = wo.x * f8tof<0>(v) + wo.y * f8tof<1>(v) +
              wo.z * f8tof<2>(v) + wo.w * f8tof<3>(v);
#pragma unroll
    for (int off = 32; off; off >>= 1) p += __shfl_xor(p, off);
    if (lane == 0) fac[r] = p;
  }
  __syncthreads();
  float al = alpha[0];
  if (t < 64) fac[t] = 1.0f + al * sigf(fac[t]);
  __syncthreads();
  int sp = t & 63;
  float f = fac[sp];
  const float* ip = in + (long)b * 1048576 + sp0 + sp;
  float* op = out + (long)b * 1048576 + sp0 + sp;
  int c0 = t >> 6;
#pragma unroll 8
  for (int c = c0; c < 256; c += 4) {
    op[c * 4096] = ip[c * 4096] * f;
  }
}

extern "C" void kernel_launch(void* const* d_in, const int* in_sizes, int n_in,
                              void* d_out, int out_size, void* d_ws, size_t ws_size,
                              hipStream_t stream) {
  const float* input   = (const float*)d_in[0];
  const float* h_Wih_f = (const float*)d_in[1];
  const float* h_Whh_f = (const float*)d_in[2];
  const float* h_b_f   = (const float*)d_in[3];
  const float* h_Wih_b = (const float*)d_in[4];
  const float* h_Whh_b = (const float*)d_in[5];
  const float* h_b_b   = (const float*)d_in[6];
  const float* v_Wih_f = (const float*)d_in[7];
  const float* v_Whh_f = (const float*)d_in[8];
  const float* v_b_f   = (const float*)d_in[9];
  const float* v_Wih_b = (const float*)d_in[10];
  const float* v_Whh_b = (const float*)d_in[11];
  const float* v_b_b   = (const float*)d_in[12];
  const float* Wr      = (const float*)d_in[13];
  const float* Wl      = (const float*)d_in[14];
  const float* alphap  = (const float*)d_in[15];

  char* ws = (char*)d_ws;
  u8*  Ah8   = (u8*)(ws + 0);              // 16,777,216 B fp8 x (stage1); later Ar8
  u8*  VF8   = (u8*)(ws + 33554432);       // 16,777,216 B fp8 evf
  u8*  Wh8   = (u8*)(ws + 67108864);       // 262,144 fp8 [2][512][256]
  u8*  Wv8   = (u8*)(ws + 67371008);       // 262,144
  u8*  WhhH8 = (u8*)(ws + 67633152);       // 131,072 fp8 [2][512][128]
  u8*  WhhV8 = (u8*)(ws + 67764224);       // 131,072
  u8*  Wrb8  = (u8*)(ws + 67895296);       // 65,536 fp8 [256][256]
  float* meansum = (float*)(ws + 67960832);  // 16 KB
  float* qavg    = (float*)(ws + 67977216);  // 16 KB
  float* pZ      = (float*)(ws + 67993600);  // 16 KB
  u8*  Av8 = (u8*)d_out;                   // stage1 fp8 output (16.7MB, dead before attfin)
  u8*  Ar8 = Ah8;                          // stage2 fp8 output over dead Ah8

  (void)hipMemsetAsync(meansum, 0, 3 * 16384, stream);  // meansum + qavg + pZ

  CvtArgs ca;
  ca.src[0] = h_Wih_f; ca.dst[0] = Wh8;           ca.n4[0] = 32768; ca.scl[0] = 1; ca.sh[0] = 6;
  ca.src[1] = h_Wih_b; ca.dst[1] = Wh8 + 131072;  ca.n4[1] = 32768; ca.scl[1] = 1; ca.sh[1] = 6;
  ca.src[2] = v_Wih_f; ca.dst[2] = Wv8;           ca.n4[2] = 32768; ca.scl[2] = 1; ca.sh[2] = 6;
  ca.src[3] = v_Wih_b; ca.dst[3] = Wv8 + 131072;  ca.n4[3] = 32768; ca.scl[3] = 1; ca.sh[3] = 6;
  ca.src[4] = h_Whh_f; ca.dst[4] = WhhH8;         ca.n4[4] = 16384; ca.scl[4] = 1; ca.sh[4] = 5;
  ca.src[5] = h_Whh_b; ca.dst[5] = WhhH8 + 65536; ca.n4[5] = 16384; ca.scl[5] = 1; ca.sh[5] = 5;
  ca.src[6] = v_Whh_f; ca.dst[6] = WhhV8;         ca.n4[6] = 16384; ca.scl[6] = 1; ca.sh[6] = 5;
  ca.src[7] = v_Whh_b; ca.dst[7] = WhhV8 + 65536; ca.n4[7] = 16384; ca.scl[7] = 1; ca.sh[7] = 5;
  ca.src[8] = Wr;      ca.dst[8] = Wrb8;          ca.n4[8] = 16384; ca.scl[8] = 2; ca.sh[8] = 6;
  k_cvt<<<dim3(128, 9), 256, 0, stream>>>(ca);

  k_tin<<<dim3(64, 16), 256, 0, stream>>>(input, Ah8, meansum);
  k_qavg<<<16, 256, 0, stream>>>(meansum, Wl, qavg);

  k_recur_f<<<dim3(64, 2), 512, 0, stream>>>(Ah8, Wh8, WhhH8, h_b_f, h_b_b, Av8);
  k_recur_f<<<dim3(64, 2), 512, 0, stream>>>(Av8, Wv8, WhhV8, v_b_f, v_b_b, Ar8);
  k_gemm8<<<1024, 256, 0, stream>>>(Ar8, Wrb8, VF8, pZ);

  k_attfin<<<1024, 256, 0, stream>>>(VF8, qavg, pZ, input, alphap, (float*)d_out);
}